// Round 1
// baseline (7900.402 us; speedup 1.0000x reference)
//
#include <hip/hip_runtime.h>
#include <math.h>

#define N_NODES 250000
#define N_EDGES 2500000
#define N_GRAPHS 512
#define BN_EPS 1e-5f

// ---------------- scatter kernels (segment_sum over edges, both directions fused)

__global__ void scatter_d6(const float* __restrict__ x,
                           const int* __restrict__ src, const int* __restrict__ dst,
                           float* __restrict__ aggF, float* __restrict__ aggB, int E)
{
    int e = blockIdx.x * blockDim.x + threadIdx.x;
    if (e >= E) return;
    int s = src[e], d = dst[e];
    #pragma unroll
    for (int f = 0; f < 6; f++) {
        atomicAdd(&aggF[d * 6 + f], x[s * 6 + f]);
        atomicAdd(&aggB[s * 6 + f], x[d * 6 + f]);
    }
}

__global__ void scatter_d32(const float* __restrict__ x,
                            const int* __restrict__ src, const int* __restrict__ dst,
                            float* __restrict__ aggF, float* __restrict__ aggB, int total)
{
    int t = blockIdx.x * blockDim.x + threadIdx.x;
    if (t >= total) return;
    int e = t >> 5;
    int f = t & 31;
    int s = src[e], d = dst[e];
    float vs = x[s * 32 + f];
    float vd = x[d * 32 + f];
    atomicAdd(&aggF[d * 32 + f], vs);
    atomicAdd(&aggB[s * 32 + f], vd);
}

// ---------------- fused dual-direction GIN MLP + BN-stats accumulation

template <int DIN>
__global__ void dgin_mlp(const float* xin,
                         const float* __restrict__ aggF, const float* __restrict__ aggB,
                         const float* __restrict__ W1f, const float* __restrict__ b1f,
                         const float* __restrict__ W2f, const float* __restrict__ b2f,
                         const float* __restrict__ W1b, const float* __restrict__ b1b,
                         const float* __restrict__ W2b, const float* __restrict__ b2b,
                         float* out, float* __restrict__ stats, int n)
{
    __shared__ __align__(16) float sW1f[DIN * 32];
    __shared__ __align__(16) float sW2f[32 * 32];
    __shared__ __align__(16) float sW1b[DIN * 32];
    __shared__ __align__(16) float sW2b[32 * 32];
    __shared__ float sb1f[32], sb2f[32], sb1b[32], sb2b[32];

    int tid = threadIdx.x;
    for (int i = tid; i < DIN * 32; i += blockDim.x) { sW1f[i] = W1f[i]; sW1b[i] = W1b[i]; }
    for (int i = tid; i < 32 * 32;  i += blockDim.x) { sW2f[i] = W2f[i]; sW2b[i] = W2b[i]; }
    if (tid < 32) { sb1f[tid] = b1f[tid]; sb2f[tid] = b2f[tid]; sb1b[tid] = b1b[tid]; sb2b[tid] = b2b[tid]; }
    __syncthreads();

    int n0 = blockIdx.x * blockDim.x + tid;
    bool valid = (n0 < n);
    int node = valid ? n0 : (n - 1);

    float xr[DIN];
    {
        const float* xp = xin + (long long)node * DIN;
        #pragma unroll
        for (int i = 0; i < DIN; i++) xr[i] = xp[i];
    }

    float o[32];

    // ---- forward direction (src -> dst aggregation)
    {
        float h[DIN];
        const float* ap = aggF + (long long)node * DIN;
        #pragma unroll
        for (int i = 0; i < DIN; i++) h[i] = xr[i] + ap[i];

        float t1[32];
        #pragma unroll
        for (int j = 0; j < 32; j++) t1[j] = sb1f[j];
        #pragma unroll
        for (int i = 0; i < DIN; i++) {
            float hv = h[i];
            const float4* wr = (const float4*)(&sW1f[i * 32]);
            #pragma unroll
            for (int q = 0; q < 8; q++) {
                float4 w = wr[q];
                t1[4*q+0] += hv * w.x; t1[4*q+1] += hv * w.y;
                t1[4*q+2] += hv * w.z; t1[4*q+3] += hv * w.w;
            }
        }
        #pragma unroll
        for (int j = 0; j < 32; j++) t1[j] = fmaxf(t1[j], 0.f);

        float o1[32];
        #pragma unroll
        for (int j = 0; j < 32; j++) o1[j] = sb2f[j];
        #pragma unroll
        for (int i = 0; i < 32; i++) {
            float hv = t1[i];
            const float4* wr = (const float4*)(&sW2f[i * 32]);
            #pragma unroll
            for (int q = 0; q < 8; q++) {
                float4 w = wr[q];
                o1[4*q+0] += hv * w.x; o1[4*q+1] += hv * w.y;
                o1[4*q+2] += hv * w.z; o1[4*q+3] += hv * w.w;
            }
        }
        #pragma unroll
        for (int j = 0; j < 32; j++) o[j] = fmaxf(o1[j], 0.f);
    }

    // ---- backward direction (dst -> src aggregation)
    {
        float h[DIN];
        const float* ap = aggB + (long long)node * DIN;
        #pragma unroll
        for (int i = 0; i < DIN; i++) h[i] = xr[i] + ap[i];

        float t1[32];
        #pragma unroll
        for (int j = 0; j < 32; j++) t1[j] = sb1b[j];
        #pragma unroll
        for (int i = 0; i < DIN; i++) {
            float hv = h[i];
            const float4* wr = (const float4*)(&sW1b[i * 32]);
            #pragma unroll
            for (int q = 0; q < 8; q++) {
                float4 w = wr[q];
                t1[4*q+0] += hv * w.x; t1[4*q+1] += hv * w.y;
                t1[4*q+2] += hv * w.z; t1[4*q+3] += hv * w.w;
            }
        }
        #pragma unroll
        for (int j = 0; j < 32; j++) t1[j] = fmaxf(t1[j], 0.f);

        float o2[32];
        #pragma unroll
        for (int j = 0; j < 32; j++) o2[j] = sb2b[j];
        #pragma unroll
        for (int i = 0; i < 32; i++) {
            float hv = t1[i];
            const float4* wr = (const float4*)(&sW2b[i * 32]);
            #pragma unroll
            for (int q = 0; q < 8; q++) {
                float4 w = wr[q];
                o2[4*q+0] += hv * w.x; o2[4*q+1] += hv * w.y;
                o2[4*q+2] += hv * w.z; o2[4*q+3] += hv * w.w;
            }
        }
        #pragma unroll
        for (int j = 0; j < 32; j++) o[j] = 0.5f * (o[j] + fmaxf(o2[j], 0.f));
    }

    if (valid) {
        float4* op = (float4*)(out + (long long)node * 32);
        #pragma unroll
        for (int q = 0; q < 8; q++)
            op[q] = make_float4(o[4*q+0], o[4*q+1], o[4*q+2], o[4*q+3]);
    }

    // ---- BN statistics: wave-level shuffle reduce, then lane-0 atomics
    int lane = tid & 63;
    #pragma unroll
    for (int f = 0; f < 32; f++) {
        float v = valid ? o[f] : 0.f;
        float v2 = v * v;
        #pragma unroll
        for (int off = 32; off > 0; off >>= 1) {
            v  += __shfl_down(v, off);
            v2 += __shfl_down(v2, off);
        }
        if (lane == 0) {
            atomicAdd(&stats[f], v);
            atomicAdd(&stats[32 + f], v2);
        }
    }
}

// ---------------- batch-norm normalization (in-place)

__global__ void bn_normalize(float* __restrict__ h, const float* __restrict__ stats,
                             const float* __restrict__ gamma, const float* __restrict__ beta, int n)
{
    __shared__ float sscale[32], sshift[32];
    int tid = threadIdx.x;
    if (tid < 32) {
        float inv_n = 1.0f / (float)n;
        float mu  = stats[tid] * inv_n;
        float var = stats[32 + tid] * inv_n - mu * mu;
        float sc  = gamma[tid] * rsqrtf(var + BN_EPS);
        sscale[tid] = sc;
        sshift[tid] = beta[tid] - mu * sc;
    }
    __syncthreads();
    int i4 = blockIdx.x * blockDim.x + tid;
    int total4 = n * 8;  // n*32/4
    if (i4 < total4) {
        float4* hp = (float4*)h;
        float4 v = hp[i4];
        int f = (i4 * 4) & 31;
        v.x = v.x * sscale[f+0] + sshift[f+0];
        v.y = v.y * sscale[f+1] + sshift[f+1];
        v.z = v.z * sscale[f+2] + sshift[f+2];
        v.w = v.w * sscale[f+3] + sshift[f+3];
        hp[i4] = v;
    }
}

// ---------------- global mean pool + head

__global__ void pool_kernel(const float* __restrict__ h, const int* __restrict__ batch,
                            float* __restrict__ psum, float* __restrict__ pcnt, int n)
{
    int t = blockIdx.x * blockDim.x + threadIdx.x;
    if (t >= n * 32) return;
    int node = t >> 5, f = t & 31;
    int g = batch[node];
    atomicAdd(&psum[g * 32 + f], h[t]);
    if (f == 0) atomicAdd(&pcnt[g], 1.0f);
}

__global__ void head_kernel(const float* __restrict__ psum, const float* __restrict__ pcnt,
                            const float* __restrict__ lbW, const float* __restrict__ lbb,
                            const float* __restrict__ lmW, const float* __restrict__ lmb,
                            float* __restrict__ out)
{
    int g = threadIdx.x;  // 512 threads, one block
    float cnt = fmaxf(pcnt[g], 1.0f);
    float inv = 1.0f / cnt;
    float p[32];
    #pragma unroll
    for (int i = 0; i < 32; i++) p[i] = psum[g * 32 + i] * inv;
    float z = lmb[0];
    #pragma unroll
    for (int k = 0; k < 16; k++) {
        float acc = lbb[k];
        #pragma unroll
        for (int i = 0; i < 32; i++) acc += p[i] * lbW[i * 16 + k];
        z += fmaxf(acc, 0.0f) * lmW[k];
    }
    out[g] = 1.0f / (1.0f + expf(-z));
}

// ---------------- launcher

extern "C" void kernel_launch(void* const* d_in, const int* in_sizes, int n_in,
                              void* d_out, int out_size, void* d_ws, size_t ws_size,
                              hipStream_t stream)
{
    const float* x    = (const float*)d_in[0];
    const int* ei     = (const int*)d_in[1];
    const int* batch  = (const int*)d_in[2];
    const int* src = ei;
    const int* dst = ei + N_EDGES;

    char* ws = (char*)d_ws;
    float* aggF  = (float*)(ws + 0);
    float* aggB  = (float*)(ws + 32000000);
    float* hbuf  = (float*)(ws + 64000000);
    float* stats = (float*)(ws + 96000000);   // 64 floats
    float* psum  = (float*)(ws + 96000512);   // 512*32 floats
    float* pcnt  = (float*)(ws + 96066048);   // 512 floats

    auto W = [&](int l, int j) { return (const float*)d_in[3 + (l - 1) * 10 + j]; };

    // ---- layer 1 (din = 6)
    hipMemsetAsync(aggF, 0, (size_t)N_NODES * 6 * 4, stream);
    hipMemsetAsync(aggB, 0, (size_t)N_NODES * 6 * 4, stream);
    hipMemsetAsync(stats, 0, 64 * 4, stream);
    scatter_d6<<<(N_EDGES + 255) / 256, 256, 0, stream>>>(x, src, dst, aggF, aggB, N_EDGES);
    dgin_mlp<6><<<(N_NODES + 255) / 256, 256, 0, stream>>>(
        x, aggF, aggB,
        W(1,0), W(1,1), W(1,2), W(1,3), W(1,4), W(1,5), W(1,6), W(1,7),
        hbuf, stats, N_NODES);
    bn_normalize<<<(N_NODES * 8 + 255) / 256, 256, 0, stream>>>(hbuf, stats, W(1,8), W(1,9), N_NODES);

    // ---- layers 2, 3 (din = 32, h in-place)
    for (int l = 2; l <= 3; l++) {
        hipMemsetAsync(aggF, 0, (size_t)N_NODES * 32 * 4, stream);
        hipMemsetAsync(aggB, 0, (size_t)N_NODES * 32 * 4, stream);
        hipMemsetAsync(stats, 0, 64 * 4, stream);
        int total = N_EDGES * 32;
        scatter_d32<<<(total + 255) / 256, 256, 0, stream>>>(hbuf, src, dst, aggF, aggB, total);
        dgin_mlp<32><<<(N_NODES + 255) / 256, 256, 0, stream>>>(
            hbuf, aggF, aggB,
            W(l,0), W(l,1), W(l,2), W(l,3), W(l,4), W(l,5), W(l,6), W(l,7),
            hbuf, stats, N_NODES);
        bn_normalize<<<(N_NODES * 8 + 255) / 256, 256, 0, stream>>>(hbuf, stats, W(l,8), W(l,9), N_NODES);
    }

    // ---- global mean pool + MLP head
    hipMemsetAsync(psum, 0, (size_t)N_GRAPHS * 32 * 4, stream);
    hipMemsetAsync(pcnt, 0, (size_t)N_GRAPHS * 4, stream);
    pool_kernel<<<(N_NODES * 32 + 255) / 256, 256, 0, stream>>>(hbuf, batch, psum, pcnt, N_NODES);
    head_kernel<<<1, 512, 0, stream>>>(psum, pcnt,
        (const float*)d_in[33], (const float*)d_in[34],
        (const float*)d_in[35], (const float*)d_in[36],
        (float*)d_out);
}

// Round 2
// 3492.237 us; speedup vs baseline: 2.2623x; 2.2623x over previous
//
#include <hip/hip_runtime.h>
#include <math.h>

#define N_NODES 250000
#define N_EDGES 2500000
#define N_GRAPHS 512
#define BN_EPS 1e-5f

// ---------------- scatter kernels (segment_sum over edges, both directions fused)

__global__ void scatter_d6(const float* __restrict__ x,
                           const int* __restrict__ src, const int* __restrict__ dst,
                           float* __restrict__ aggF, float* __restrict__ aggB, int E)
{
    int e = blockIdx.x * blockDim.x + threadIdx.x;
    if (e >= E) return;
    int s = src[e], d = dst[e];
    #pragma unroll
    for (int f = 0; f < 6; f++) {
        atomicAdd(&aggF[d * 6 + f], x[s * 6 + f]);
        atomicAdd(&aggB[s * 6 + f], x[d * 6 + f]);
    }
}

__global__ void scatter_d32(const float* __restrict__ x,
                            const int* __restrict__ src, const int* __restrict__ dst,
                            float* __restrict__ aggF, float* __restrict__ aggB, int total)
{
    int t = blockIdx.x * blockDim.x + threadIdx.x;
    if (t >= total) return;
    int e = t >> 5;
    int f = t & 31;
    int s = src[e], d = dst[e];
    float vs = x[s * 32 + f];
    float vd = x[d * 32 + f];
    atomicAdd(&aggF[d * 32 + f], vs);
    atomicAdd(&aggB[s * 32 + f], vd);
}

// ---------------- fused dual-direction GIN MLP + BN-stats accumulation
// __launch_bounds__(256,1): per-thread live set is ~140 floats (o/t1/o1/h/xr);
// the default VGPR cap of 64 caused ~66 MB of scratch spill per dispatch (R1:
// WRITE_SIZE 98 MB vs 32 MB ideal, 1585 us latency-bound). With 1 wave/EU the
// allocator gets up to 512 VGPRs -> no spill.

template <int DIN>
__global__ __launch_bounds__(256, 1)
void dgin_mlp(const float* xin,
              const float* __restrict__ aggF, const float* __restrict__ aggB,
              const float* __restrict__ W1f, const float* __restrict__ b1f,
              const float* __restrict__ W2f, const float* __restrict__ b2f,
              const float* __restrict__ W1b, const float* __restrict__ b1b,
              const float* __restrict__ W2b, const float* __restrict__ b2b,
              float* out, float* __restrict__ stats, int n)
{
    __shared__ __align__(16) float sW1f[DIN * 32];
    __shared__ __align__(16) float sW2f[32 * 32];
    __shared__ __align__(16) float sW1b[DIN * 32];
    __shared__ __align__(16) float sW2b[32 * 32];
    __shared__ float sb1f[32], sb2f[32], sb1b[32], sb2b[32];
    __shared__ float sred[4 * 64];  // cross-wave BN-stat reduction

    int tid = threadIdx.x;
    for (int i = tid; i < DIN * 32; i += blockDim.x) { sW1f[i] = W1f[i]; sW1b[i] = W1b[i]; }
    for (int i = tid; i < 32 * 32;  i += blockDim.x) { sW2f[i] = W2f[i]; sW2b[i] = W2b[i]; }
    if (tid < 32) { sb1f[tid] = b1f[tid]; sb2f[tid] = b2f[tid]; sb1b[tid] = b1b[tid]; sb2b[tid] = b2b[tid]; }
    __syncthreads();

    int n0 = blockIdx.x * blockDim.x + tid;
    bool valid = (n0 < n);
    int node = valid ? n0 : (n - 1);

    float xr[DIN];
    {
        const float* xp = xin + (long long)node * DIN;
        #pragma unroll
        for (int i = 0; i < DIN; i++) xr[i] = xp[i];
    }

    float o[32];

    // ---- forward direction (src -> dst aggregation)
    {
        float h[DIN];
        const float* ap = aggF + (long long)node * DIN;
        #pragma unroll
        for (int i = 0; i < DIN; i++) h[i] = xr[i] + ap[i];

        float t1[32];
        #pragma unroll
        for (int j = 0; j < 32; j++) t1[j] = sb1f[j];
        #pragma unroll
        for (int i = 0; i < DIN; i++) {
            float hv = h[i];
            const float4* wr = (const float4*)(&sW1f[i * 32]);
            #pragma unroll
            for (int q = 0; q < 8; q++) {
                float4 w = wr[q];
                t1[4*q+0] += hv * w.x; t1[4*q+1] += hv * w.y;
                t1[4*q+2] += hv * w.z; t1[4*q+3] += hv * w.w;
            }
        }
        #pragma unroll
        for (int j = 0; j < 32; j++) t1[j] = fmaxf(t1[j], 0.f);

        float o1[32];
        #pragma unroll
        for (int j = 0; j < 32; j++) o1[j] = sb2f[j];
        #pragma unroll
        for (int i = 0; i < 32; i++) {
            float hv = t1[i];
            const float4* wr = (const float4*)(&sW2f[i * 32]);
            #pragma unroll
            for (int q = 0; q < 8; q++) {
                float4 w = wr[q];
                o1[4*q+0] += hv * w.x; o1[4*q+1] += hv * w.y;
                o1[4*q+2] += hv * w.z; o1[4*q+3] += hv * w.w;
            }
        }
        #pragma unroll
        for (int j = 0; j < 32; j++) o[j] = fmaxf(o1[j], 0.f);
    }

    // ---- backward direction (dst -> src aggregation)
    {
        float h[DIN];
        const float* ap = aggB + (long long)node * DIN;
        #pragma unroll
        for (int i = 0; i < DIN; i++) h[i] = xr[i] + ap[i];

        float t1[32];
        #pragma unroll
        for (int j = 0; j < 32; j++) t1[j] = sb1b[j];
        #pragma unroll
        for (int i = 0; i < DIN; i++) {
            float hv = h[i];
            const float4* wr = (const float4*)(&sW1b[i * 32]);
            #pragma unroll
            for (int q = 0; q < 8; q++) {
                float4 w = wr[q];
                t1[4*q+0] += hv * w.x; t1[4*q+1] += hv * w.y;
                t1[4*q+2] += hv * w.z; t1[4*q+3] += hv * w.w;
            }
        }
        #pragma unroll
        for (int j = 0; j < 32; j++) t1[j] = fmaxf(t1[j], 0.f);

        float o2[32];
        #pragma unroll
        for (int j = 0; j < 32; j++) o2[j] = sb2b[j];
        #pragma unroll
        for (int i = 0; i < 32; i++) {
            float hv = t1[i];
            const float4* wr = (const float4*)(&sW2b[i * 32]);
            #pragma unroll
            for (int q = 0; q < 8; q++) {
                float4 w = wr[q];
                o2[4*q+0] += hv * w.x; o2[4*q+1] += hv * w.y;
                o2[4*q+2] += hv * w.z; o2[4*q+3] += hv * w.w;
            }
        }
        #pragma unroll
        for (int j = 0; j < 32; j++) o[j] = 0.5f * (o[j] + fmaxf(o2[j], 0.f));
    }

    if (valid) {
        float4* op = (float4*)(out + (long long)node * 32);
        #pragma unroll
        for (int q = 0; q < 8; q++)
            op[q] = make_float4(o[4*q+0], o[4*q+1], o[4*q+2], o[4*q+3]);
    }

    // ---- BN statistics: wave shuffle reduce -> LDS cross-wave reduce -> 64 atomics/block
    int lane = tid & 63;
    int wave = tid >> 6;
    #pragma unroll
    for (int f = 0; f < 32; f++) {
        float v = valid ? o[f] : 0.f;
        float v2 = v * v;
        #pragma unroll
        for (int off = 32; off > 0; off >>= 1) {
            v  += __shfl_down(v, off);
            v2 += __shfl_down(v2, off);
        }
        if (lane == 0) {
            sred[wave * 64 + f]      = v;
            sred[wave * 64 + 32 + f] = v2;
        }
    }
    __syncthreads();
    if (tid < 64) {
        float acc = sred[tid] + sred[64 + tid] + sred[128 + tid] + sred[192 + tid];
        atomicAdd(&stats[tid], acc);
    }
}

// ---------------- batch-norm normalization (in-place)

__global__ void bn_normalize(float* __restrict__ h, const float* __restrict__ stats,
                             const float* __restrict__ gamma, const float* __restrict__ beta, int n)
{
    __shared__ float sscale[32], sshift[32];
    int tid = threadIdx.x;
    if (tid < 32) {
        float inv_n = 1.0f / (float)n;
        float mu  = stats[tid] * inv_n;
        float var = stats[32 + tid] * inv_n - mu * mu;
        float sc  = gamma[tid] * rsqrtf(var + BN_EPS);
        sscale[tid] = sc;
        sshift[tid] = beta[tid] - mu * sc;
    }
    __syncthreads();
    int i4 = blockIdx.x * blockDim.x + tid;
    int total4 = n * 8;  // n*32/4
    if (i4 < total4) {
        float4* hp = (float4*)h;
        float4 v = hp[i4];
        int f = (i4 * 4) & 31;
        v.x = v.x * sscale[f+0] + sshift[f+0];
        v.y = v.y * sscale[f+1] + sshift[f+1];
        v.z = v.z * sscale[f+2] + sshift[f+2];
        v.w = v.w * sscale[f+3] + sshift[f+3];
        hp[i4] = v;
    }
}

// ---------------- global mean pool + head

__global__ void pool_kernel(const float* __restrict__ h, const int* __restrict__ batch,
                            float* __restrict__ psum, float* __restrict__ pcnt, int n)
{
    int t = blockIdx.x * blockDim.x + threadIdx.x;
    if (t >= n * 32) return;
    int node = t >> 5, f = t & 31;
    int g = batch[node];
    atomicAdd(&psum[g * 32 + f], h[t]);
    if (f == 0) atomicAdd(&pcnt[g], 1.0f);
}

__global__ void head_kernel(const float* __restrict__ psum, const float* __restrict__ pcnt,
                            const float* __restrict__ lbW, const float* __restrict__ lbb,
                            const float* __restrict__ lmW, const float* __restrict__ lmb,
                            float* __restrict__ out)
{
    int g = threadIdx.x;  // 512 threads, one block
    float cnt = fmaxf(pcnt[g], 1.0f);
    float inv = 1.0f / cnt;
    float p[32];
    #pragma unroll
    for (int i = 0; i < 32; i++) p[i] = psum[g * 32 + i] * inv;
    float z = lmb[0];
    #pragma unroll
    for (int k = 0; k < 16; k++) {
        float acc = lbb[k];
        #pragma unroll
        for (int i = 0; i < 32; i++) acc += p[i] * lbW[i * 16 + k];
        z += fmaxf(acc, 0.0f) * lmW[k];
    }
    out[g] = 1.0f / (1.0f + expf(-z));
}

// ---------------- launcher

extern "C" void kernel_launch(void* const* d_in, const int* in_sizes, int n_in,
                              void* d_out, int out_size, void* d_ws, size_t ws_size,
                              hipStream_t stream)
{
    const float* x    = (const float*)d_in[0];
    const int* ei     = (const int*)d_in[1];
    const int* batch  = (const int*)d_in[2];
    const int* src = ei;
    const int* dst = ei + N_EDGES;

    char* ws = (char*)d_ws;
    float* aggF  = (float*)(ws + 0);
    float* aggB  = (float*)(ws + 32000000);
    float* hbuf  = (float*)(ws + 64000000);
    float* stats = (float*)(ws + 96000000);   // 64 floats
    float* psum  = (float*)(ws + 96000512);   // 512*32 floats
    float* pcnt  = (float*)(ws + 96066048);   // 512 floats

    auto W = [&](int l, int j) { return (const float*)d_in[3 + (l - 1) * 10 + j]; };

    // ---- layer 1 (din = 6)
    hipMemsetAsync(aggF, 0, (size_t)N_NODES * 6 * 4, stream);
    hipMemsetAsync(aggB, 0, (size_t)N_NODES * 6 * 4, stream);
    hipMemsetAsync(stats, 0, 64 * 4, stream);
    scatter_d6<<<(N_EDGES + 255) / 256, 256, 0, stream>>>(x, src, dst, aggF, aggB, N_EDGES);
    dgin_mlp<6><<<(N_NODES + 255) / 256, 256, 0, stream>>>(
        x, aggF, aggB,
        W(1,0), W(1,1), W(1,2), W(1,3), W(1,4), W(1,5), W(1,6), W(1,7),
        hbuf, stats, N_NODES);
    bn_normalize<<<(N_NODES * 8 + 255) / 256, 256, 0, stream>>>(hbuf, stats, W(1,8), W(1,9), N_NODES);

    // ---- layers 2, 3 (din = 32, h in-place)
    for (int l = 2; l <= 3; l++) {
        hipMemsetAsync(aggF, 0, (size_t)N_NODES * 32 * 4, stream);
        hipMemsetAsync(aggB, 0, (size_t)N_NODES * 32 * 4, stream);
        hipMemsetAsync(stats, 0, 64 * 4, stream);
        int total = N_EDGES * 32;
        scatter_d32<<<(total + 255) / 256, 256, 0, stream>>>(hbuf, src, dst, aggF, aggB, total);
        dgin_mlp<32><<<(N_NODES + 255) / 256, 256, 0, stream>>>(
            hbuf, aggF, aggB,
            W(l,0), W(l,1), W(l,2), W(l,3), W(l,4), W(l,5), W(l,6), W(l,7),
            hbuf, stats, N_NODES);
        bn_normalize<<<(N_NODES * 8 + 255) / 256, 256, 0, stream>>>(hbuf, stats, W(l,8), W(l,9), N_NODES);
    }

    // ---- global mean pool + MLP head
    hipMemsetAsync(psum, 0, (size_t)N_GRAPHS * 32 * 4, stream);
    hipMemsetAsync(pcnt, 0, (size_t)N_GRAPHS * 4, stream);
    pool_kernel<<<(N_NODES * 32 + 255) / 256, 256, 0, stream>>>(hbuf, batch, psum, pcnt, N_NODES);
    head_kernel<<<1, 512, 0, stream>>>(psum, pcnt,
        (const float*)d_in[33], (const float*)d_in[34],
        (const float*)d_in[35], (const float*)d_in[36],
        (float*)d_out);
}